// Round 1
// baseline (712.354 us; speedup 1.0000x reference)
//
#include <hip/hip_runtime.h>
#include <float.h>

#define NN 5000
#define NE 50000
#define C 64
#define CHW 3072       // 64*12*4
#define CHW4 768       // CHW/4
#define SPLIT 25
#define NPS 200        // 5000/25

// ---------------- CSR build ----------------
__global__ void hist_kernel(const int* __restrict__ dst, int* __restrict__ cnt) {
  int e = blockIdx.x * 256 + threadIdx.x;
  if (e < NE) atomicAdd(&cnt[dst[e]], 1);
}

__global__ void scan_kernel(const int* __restrict__ cnt, int* __restrict__ off, int* __restrict__ cur) {
  __shared__ int tsum[256];
  int t = threadIdx.x;
  constexpr int PER = 20; // ceil(5000/256)
  int base = t * PER;
  int vals[PER];
  int local = 0;
#pragma unroll
  for (int i = 0; i < PER; i++) {
    int idx = base + i;
    int v = (idx < NN) ? cnt[idx] : 0;
    vals[i] = local;
    local += v;
  }
  tsum[t] = local;
  __syncthreads();
  for (int o = 1; o < 256; o <<= 1) {
    int v = (t >= o) ? tsum[t - o] : 0;
    __syncthreads();
    tsum[t] += v;
    __syncthreads();
  }
  int excl = (t == 0) ? 0 : tsum[t - 1];
#pragma unroll
  for (int i = 0; i < PER; i++) {
    int idx = base + i;
    if (idx < NN) {
      int o2 = excl + vals[i];
      off[idx] = o2;
      cur[idx] = o2;
    }
  }
  if (t == 255) off[NN] = excl + local;
}

__global__ void scatter_kernel(const int* __restrict__ dst, int* __restrict__ cur, int* __restrict__ eids) {
  int e = blockIdx.x * 256 + threadIdx.x;
  if (e < NE) {
    int p = atomicAdd(&cur[dst[e]], 1);
    eids[p] = e;
  }
}

// ---------------- BatchNorm stats ----------------
__global__ void bn_stats_kernel(const float* __restrict__ hv, float* __restrict__ stats) {
  int c = blockIdx.x / SPLIT, s = blockIdx.x % SPLIT;
  int n0 = s * NPS;
  const float4* hv4 = (const float4*)hv;
  float sum = 0.f, ss = 0.f;
  for (int i = threadIdx.x; i < NPS * 12; i += 256) {
    int n = n0 + i / 12, p = i % 12;
    float4 v = hv4[(size_t)n * CHW4 + c * 12 + p];
    sum += v.x + v.y + v.z + v.w;
    ss += v.x * v.x + v.y * v.y + v.z * v.z + v.w * v.w;
  }
  __shared__ float rs[256], rq[256];
  rs[threadIdx.x] = sum;
  rq[threadIdx.x] = ss;
  __syncthreads();
  for (int o = 128; o > 0; o >>= 1) {
    if (threadIdx.x < o) {
      rs[threadIdx.x] += rs[threadIdx.x + o];
      rq[threadIdx.x] += rq[threadIdx.x + o];
    }
    __syncthreads();
  }
  if (threadIdx.x == 0) {
    atomicAdd(&stats[c], rs[0]);
    atomicAdd(&stats[C + c], rq[0]);
  }
}

__global__ void bn_finalize_kernel(const float* __restrict__ stats, const float* __restrict__ gamma,
                                   const float* __restrict__ beta, float* __restrict__ sc,
                                   float* __restrict__ sh) {
  int c = threadIdx.x;
  if (c < C) {
    const float inv = 1.f / 240000.f;
    float mu = stats[c] * inv;
    float var = stats[C + c] * inv - mu * mu;
    float scale = gamma[c] * rsqrtf(var + 1e-5f);
    sc[c] = scale;
    sh[c] = beta[c] - mu * scale;
  }
}

// ---------------- Fused GENConv layer ----------------
// One block per node: online-softmax aggregation over incoming edges,
// fused BN+ReLU on the fly, then 64x64 channel linear + bias + residual.
__global__ __launch_bounds__(256) void aggregate_kernel(
    const float* __restrict__ hv, const float* __restrict__ he,
    const int* __restrict__ srcArr, const int* __restrict__ eids, const int* __restrict__ off,
    const float* __restrict__ Wg, const float* __restrict__ bg,
    const float* __restrict__ sc, const float* __restrict__ sh,
    float* __restrict__ hvNext) {
  __shared__ float Wl[4096];
  __shared__ float fl[CHW];
  __shared__ float scl[64], shl[64];
  int n = blockIdx.x, t = threadIdx.x;
  for (int i = t; i < 4096; i += 256) Wl[i] = Wg[i];
  if (t < 64) {
    scl[t] = sc[t];
    shl[t] = sh[t];
  }
  __syncthreads();

  const float4* hv4 = (const float4*)hv;
  const float4* he4 = (const float4*)he;

  float hold[12], h1[12];
  float scv[3], shv[3];
#pragma unroll
  for (int j = 0; j < 3; j++) {
    int q = t + j * 256;
    int c = q / 12;
    scv[j] = scl[c];
    shv[j] = shl[c];
    float4 v = hv4[(size_t)n * CHW4 + q];
    hold[j * 4 + 0] = v.x; hold[j * 4 + 1] = v.y; hold[j * 4 + 2] = v.z; hold[j * 4 + 3] = v.w;
    h1[j * 4 + 0] = fmaxf(v.x * scv[j] + shv[j], 0.f);
    h1[j * 4 + 1] = fmaxf(v.y * scv[j] + shv[j], 0.f);
    h1[j * 4 + 2] = fmaxf(v.z * scv[j] + shv[j], 0.f);
    h1[j * 4 + 3] = fmaxf(v.w * scv[j] + shv[j], 0.f);
  }

  float M[12], S[12], T[12];
#pragma unroll
  for (int i = 0; i < 12; i++) {
    M[i] = -FLT_MAX;
    S[i] = 0.f;
    T[i] = 0.f;
  }

  int e0 = off[n], e1 = off[n + 1];
  for (int k = e0; k < e1; k++) {
    int e = eids[k];
    int s = srcArr[e];
    size_t hb = (size_t)s * CHW4, eb = (size_t)e * CHW4;
#pragma unroll
    for (int j = 0; j < 3; j++) {
      int q = t + j * 256;
      float4 a = hv4[hb + q];
      float4 b = he4[eb + q];
      float av[4] = {a.x, a.y, a.z, a.w};
      float bv[4] = {b.x, b.y, b.z, b.w};
#pragma unroll
      for (int u = 0; u < 4; u++) {
        float x = fmaxf(av[u] * scv[j] + shv[j], 0.f);
        float m = fmaxf(x + bv[u], 0.f) + 1e-7f;
        int idx = j * 4 + u;
        float nM = fmaxf(M[idx], m);
        float f1 = __expf(M[idx] - nM);
        float f2 = __expf(m - nM);
        S[idx] = S[idx] * f1 + f2;
        T[idx] = T[idx] * f1 + f2 * m;
        M[idx] = nM;
      }
    }
  }

  bool hasE = e1 > e0;
#pragma unroll
  for (int j = 0; j < 3; j++) {
    int q = t + j * 256;
    float4 f;
    int idx = j * 4;
    f.x = h1[idx + 0] + (hasE ? T[idx + 0] / S[idx + 0] : 0.f);
    f.y = h1[idx + 1] + (hasE ? T[idx + 1] / S[idx + 1] : 0.f);
    f.z = h1[idx + 2] + (hasE ? T[idx + 2] / S[idx + 2] : 0.f);
    f.w = h1[idx + 3] + (hasE ? T[idx + 3] / S[idx + 3] : 0.f);
    ((float4*)fl)[q] = f;
  }
  __syncthreads();

#pragma unroll
  for (int j = 0; j < 3; j++) {
    int q = t + j * 256;
    int o = q / 12, hb2 = q % 12;
    float bias = bg[o];
    float4 acc;
    acc.x = acc.y = acc.z = acc.w = bias;
    const float4* f4 = (const float4*)fl;
    for (int c2 = 0; c2 < 64; c2++) {
      float w = Wl[c2 * 64 + o];
      float4 fv = f4[c2 * 12 + hb2];
      acc.x += w * fv.x;
      acc.y += w * fv.y;
      acc.z += w * fv.z;
      acc.w += w * fv.w;
    }
    acc.x += hold[j * 4 + 0];
    acc.y += hold[j * 4 + 1];
    acc.z += hold[j * 4 + 2];
    acc.w += hold[j * 4 + 3];
    ((float4*)hvNext)[(size_t)n * CHW4 + q] = acc;
  }
}

// ---------------- Output projection ----------------
__global__ __launch_bounds__(256) void out_kernel(const float* __restrict__ hv,
                                                  const float* __restrict__ oW,
                                                  const float* __restrict__ ob,
                                                  float* __restrict__ out) {
  __shared__ float hl[CHW];
  __shared__ float Wl[768];
  __shared__ float mw[768];
  int n = blockIdx.x, t = threadIdx.x;
  const float4* hv4 = (const float4*)hv;
  for (int i = t; i < 768; i += 256) Wl[i] = oW[i];
  float4* hl4 = (float4*)hl;
#pragma unroll
  for (int j = 0; j < 3; j++) hl4[t + j * 256] = hv4[(size_t)n * CHW4 + t + j * 256];
  __syncthreads();
  for (int i = t; i < 768; i += 256) {
    float4 v = hl4[i];
    mw[i] = (v.x + v.y + v.z + v.w) * 0.25f;
  }
  __syncthreads();
  if (t < 144) {
    int o = t / 12, hb = t % 12;
    float bias = ob[o];
    float4 acc;
    acc.x = acc.y = acc.z = acc.w = bias;
    for (int c2 = 0; c2 < 64; c2++) {
      float4 v = hl4[c2 * 12 + hb];
      float wv = Wl[c2 * 12 + o] * mw[c2 * 12 + hb];
      acc.x += wv * v.x;
      acc.y += wv * v.y;
      acc.z += wv * v.z;
      acc.w += wv * v.w;
    }
    ((float4*)out)[(size_t)n * 144 + t] = acc;
  }
}

extern "C" void kernel_launch(void* const* d_in, const int* in_sizes, int n_in,
                              void* d_out, int out_size, void* d_ws, size_t ws_size,
                              hipStream_t stream) {
  const float* node_feats = (const float*)d_in[0];
  const float* edge_feats = (const float*)d_in[1];
  const int* src = (const int*)d_in[2];
  const int* dst = (const int*)d_in[3];
  const float* bn_gamma = (const float*)d_in[4];
  const float* bn_beta = (const float*)d_in[5];
  const float* gen_W = (const float*)d_in[6];
  const float* gen_b = (const float*)d_in[7];
  const float* out_W = (const float*)d_in[8];
  const float* out_b = (const float*)d_in[9];
  float* out = (float*)d_out;

  char* ws = (char*)d_ws;
  float* hvA = (float*)ws;                         // 61,440,000 B
  float* hvB = (float*)(ws + 61440000);            // 61,440,000 B
  float* stats = (float*)(ws + 122880000);         // 512 B
  float* sc = (float*)(ws + 122880512);            // 256 B
  float* sh = (float*)(ws + 122880768);            // 256 B
  int* cnt = (int*)(ws + 122881024);               // 20,000 B
  int* off = (int*)(ws + 122901024);               // 20,004 B
  int* cur = (int*)(ws + 122921040);               // 20,000 B
  int* eids = (int*)(ws + 122941056);              // 200,000 B

  // CSR build (dst -> edge list)
  hipMemsetAsync(cnt, 0, NN * sizeof(int), stream);
  hist_kernel<<<(NE + 255) / 256, 256, 0, stream>>>(dst, cnt);
  scan_kernel<<<1, 256, 0, stream>>>(cnt, off, cur);
  scatter_kernel<<<(NE + 255) / 256, 256, 0, stream>>>(dst, cur, eids);

  const float* hvPrev = node_feats;
  float* bufs[2] = {hvA, hvB};
  for (int l = 0; l < 3; l++) {
    hipMemsetAsync(stats, 0, 2 * C * sizeof(float), stream);
    bn_stats_kernel<<<C * SPLIT, 256, 0, stream>>>(hvPrev, stats);
    bn_finalize_kernel<<<1, 64, 0, stream>>>(stats, bn_gamma + l * C, bn_beta + l * C, sc, sh);
    float* hvNext = bufs[l & 1];
    aggregate_kernel<<<NN, 256, 0, stream>>>(hvPrev, edge_feats, src, eids, off,
                                             gen_W + l * C * C, gen_b + l * C, sc, sh, hvNext);
    hvPrev = hvNext;
  }
  out_kernel<<<NN, 256, 0, stream>>>(hvPrev, out_W, out_b, out);
}